// Round 7
// baseline (2529.579 us; speedup 1.0000x reference)
//
#include <hip/hip_runtime.h>
#include <stdint.h>

constexpr int kS = 512;   // sequence length
constexpr int kB = 32;    // batch (only element 0 decoded)
constexpr int kH = 512;   // hidden
constexpr int kV = 64;    // tags

// ---------------------------------------------------------------------------
// ws layout (floats):
//   X    [512][512]     @ 0        (262144)
//   H0   [2][512][512]  @ 262144   (524288)  agent/MALL handoff + layer-1 input
//   H1   [2][512][512]  @ 786432   (524288)
//   LOG  [512][64]      @ 1310720  (32768)
// Total 5.4 MB. H0..H1 memset to 0xFF each launch (sentinel = NaN,
// unreachable for computed |h|<1).
//
// Evidence ledger:
//  R0 champion 2022us (k_rec ~950; 512 pollers, sc0 L2 prelude + MALL).
//  R1 (election + 64-try L2 spin)        k_rec 1190-1214  (+25%)
//  R2 (MALL-only, 512 pollers)           k_rec  993       (+4.5%) <- BASELINE
//  R4 (wave-autonomous, 16x poll xacts)  k_rec 4966       (5x, FETCH 6x)
//  R5 (election + champion verbatim)     k_rec 1027       (+8%)
//  R6 (sc0 dwordx4 poll storm)           container died 2x -> asm suspect
// => poll PATH worth <5%; poll TRANSACTION COUNT is the scaling variable.
// This round: R2 structure + designated segment pollers, ZERO inline asm in
// k_rec (only __hip_atomic_load/store, proven in R2). Waves 0-1 poll 4
// dwords each (4 independent agent spins, issued before the input matvec),
// deposit h(t_prev) into LDS hbuf; all waves read h from LDS. 4x fewer poll
// transactions per producer line. Cell on wave 7 (never a poller); second
// barrier closes the champion's part[] clobber race.
// ---------------------------------------------------------------------------

__device__ __forceinline__ float fast_sigmoid(float x) {
  return __builtin_amdgcn_rcpf(1.0f + __expf(-x));
}
__device__ __forceinline__ float fast_tanh(float x) {
  return 1.0f - 2.0f * __builtin_amdgcn_rcpf(1.0f + __expf(2.0f * x));
}
__device__ __forceinline__ float bcast(float v, int k) {
  return __uint_as_float(__builtin_amdgcn_readlane(__float_as_uint(v), k));
}
__device__ __forceinline__ unsigned ld_agent(const unsigned* p) {
  return __hip_atomic_load(p, __ATOMIC_RELAXED, __HIP_MEMORY_SCOPE_AGENT);
}

__global__ __launch_bounds__(128) void k_embed(const int* __restrict__ src,
                                               const float* __restrict__ emb,
                                               float* __restrict__ X) {
  const int t = blockIdx.x;
  const int s = src[t * kB];  // batch 0 token
  const float4* e = (const float4*)(emb + (size_t)s * 512);
  float4* x = (float4*)(X + (size_t)t * 512);
  x[threadIdx.x] = e[threadIdx.x];
}

// Fused recurrence, segment-poller variant (no inline asm).
// Grid = 256 blocks, only b%8 in {0,1} work (dir = b%8, wg = b>>3 in [0,32));
// all co-resident (1 block/CU) -> spins deadlock-free. wg owns h[wg*16..+16)
// -> 64 gate rows; lane l of each wave owns gate row l; wave wv owns k-slice
// [wv*64,+64) of Whh and [wv*ZPW,+ZPW) of Wih (registers, loaded once).
// Per step: z prefetch; (waves 0-1) issue 4 h-poll loads; input matvec
// (hides poll round-trip); pollers spin-complete -> LDS hbuf; barrier;
// hreg = hbuf[tid]; recurrent matvec; part write; barrier; wave 7 reduce +
// cell + single agent publish (16 dwords = one 64B line per block per step).
template <int KZ>
__global__ __launch_bounds__(512, 1) void k_rec(
    const float* __restrict__ Z0,   // layer0: X; layer1: H0 fwd
    const float* __restrict__ Z1,   // layer1: H0 bwd (unused for KZ==512)
    const float* __restrict__ Wih,  // [2][2048][KZ]
    const float* __restrict__ Whh,  // [2][2048][512]
    const float* __restrict__ bih,  // [2][2048]
    const float* __restrict__ bhh,  // [2][2048]
    float* __restrict__ H) {        // [2][512][512] agent/MALL handoff
  constexpr int ZPW = KZ / 8;       // z k-slice per wave (64 or 128)
  __shared__ float part[64 * 9];    // [row][wave], stride 9: odd -> no 4-way
  __shared__ float hbuf[512];       // h(t_prev) broadcast buffer
  const int b = blockIdx.x;
  const int xslot = b & 7;
  if (xslot > 1) return;            // workers only on slots 0/1
  const int dir = xslot, wg = b >> 3;
  const int tid = threadIdx.x;
  const int wv = tid >> 6, l = tid & 63;
  const float* WihB = Wih + (size_t)dir * 2048 * KZ;
  const float* WhhB = Whh + (size_t)dir * 2048 * 512;
  float* Hb = H + (size_t)dir * kS * kH;
  const int grow = (l >> 4) * 512 + wg * 16 + (l & 15);

  // --- one-time weight loads into registers ---
  float ww[64];
  {
    const float* wp = WhhB + (size_t)grow * 512 + wv * 64;
#pragma unroll
    for (int i = 0; i < 64; i += 4) {
      const float4 v = *(const float4*)(wp + i);
      ww[i] = v.x; ww[i + 1] = v.y; ww[i + 2] = v.z; ww[i + 3] = v.w;
    }
  }
  float zw[ZPW];
  {
    const float* zp = WihB + (size_t)grow * KZ + wv * ZPW;
#pragma unroll
    for (int i = 0; i < ZPW; i += 4) {
      const float4 v = *(const float4*)(zp + i);
      zw[i] = v.x; zw[i + 1] = v.y; zw[i + 2] = v.z; zw[i + 3] = v.w;
    }
  }
  float bias = 0.0f;
  if (wv == 7) bias = bih[dir * 2048 + grow] + bhh[dir * 2048 + grow];
  float cstate = 0.0f;  // live in wave 7, lanes < 16

  hbuf[tid] = 0.0f;  // s=0 reads zeros (own-thread write, read by self)

  const float* zbase = (KZ == 512) ? Z0 : ((wv < 4) ? Z0 : Z1);
  const int zoff = (KZ == 512) ? tid : ((wv & 3) * 128 + l);

  const int t0 = dir ? (kS - 1) : 0;
  float zc0 = zbase[(size_t)t0 * 512 + zoff];
  float zc1 = (KZ == 1024) ? zbase[(size_t)t0 * 512 + zoff + 64] : 0.0f;

  for (int s = 0; s < kS; s++) {
    const int t = dir ? (kS - 1 - s) : s;
    int tn = dir ? (t - 1) : (t + 1);
    if (tn < 0) tn = 0;
    if (tn > kS - 1) tn = kS - 1;
    // next-step z prefetch (independent, hides under matvec/poll)
    const float zn0 = zbase[(size_t)tn * 512 + zoff];
    const float zn1 = (KZ == 1024) ? zbase[(size_t)tn * 512 + zoff + 64] : 0.0f;

    // --- pollers (waves 0-1): issue this step's 4 h-poll loads early ---
    unsigned u0 = 0, u1 = 0, u2 = 0, u3 = 0;
    const unsigned* gp = nullptr;
    if (s > 0 && tid < 128) {
      const int tp = dir ? (t + 1) : (t - 1);
      gp = (const unsigned*)(Hb + (size_t)tp * kH) + tid * 4;
      u0 = ld_agent(gp + 0);
      u1 = ld_agent(gp + 1);
      u2 = ld_agent(gp + 2);
      u3 = ld_agent(gp + 3);
    }

    // --- input-gate matvec: independent of h, hides poll round-trip ---
    float a0 = 0.f, a1 = 0.f, a2 = 0.f, a3 = 0.f;
#pragma unroll
    for (int k = 0; k < 64; k += 4) {
      a0 += zw[k + 0] * bcast(zc0, k + 0);
      a1 += zw[k + 1] * bcast(zc0, k + 1);
      a2 += zw[k + 2] * bcast(zc0, k + 2);
      a3 += zw[k + 3] * bcast(zc0, k + 3);
    }
    if (KZ == 1024) {
#pragma unroll
      for (int k = 0; k < 64; k += 4) {
        a0 += zw[64 + k + 0] * bcast(zc1, k + 0);
        a1 += zw[64 + k + 1] * bcast(zc1, k + 1);
        a2 += zw[64 + k + 2] * bcast(zc1, k + 2);
        a3 += zw[64 + k + 3] * bcast(zc1, k + 3);
      }
    }

    // --- pollers: spin-complete and deposit into LDS ---
    if (s > 0 && tid < 128) {
      while (u0 == 0xFFFFFFFFu) u0 = ld_agent(gp + 0);
      while (u1 == 0xFFFFFFFFu) u1 = ld_agent(gp + 1);
      while (u2 == 0xFFFFFFFFu) u2 = ld_agent(gp + 2);
      while (u3 == 0xFFFFFFFFu) u3 = ld_agent(gp + 3);
      hbuf[tid * 4 + 0] = __uint_as_float(u0);
      hbuf[tid * 4 + 1] = __uint_as_float(u1);
      hbuf[tid * 4 + 2] = __uint_as_float(u2);
      hbuf[tid * 4 + 3] = __uint_as_float(u3);
    }
    __syncthreads();  // hbuf(t_prev) complete

    // --- recurrent matvec from LDS broadcast ---
    const float hreg = hbuf[tid];
#pragma unroll
    for (int k = 0; k < 64; k += 4) {
      a0 += ww[k + 0] * bcast(hreg, k + 0);
      a1 += ww[k + 1] * bcast(hreg, k + 1);
      a2 += ww[k + 2] * bcast(hreg, k + 2);
      a3 += ww[k + 3] * bcast(hreg, k + 3);
    }
    part[l * 9 + wv] = (a0 + a1) + (a2 + a3);
    __syncthreads();  // part complete; also fences hbuf reuse
    // waves 0-6 fall through to next step immediately; wave 7 does the cell.
    if (wv == 7) {
      float ssum = bias;
#pragma unroll
      for (int w = 0; w < 8; w++) ssum += part[l * 9 + w];
      const float sf = __shfl(ssum, (l + 16) & 63);
      const float sg = __shfl(ssum, (l + 32) & 63);
      const float so = __shfl(ssum, (l + 48) & 63);
      if (l < 16) {
        const float ig = fast_sigmoid(ssum);
        const float fg = fast_sigmoid(sf);
        const float og = fast_sigmoid(so);
        cstate = fg * cstate + ig * fast_tanh(sg);
        const float h = og * fast_tanh(cstate);
        unsigned* gq = (unsigned*)(Hb + (size_t)t * kH) + wg * 16 + l;
        __hip_atomic_store(gq, __float_as_uint(h), __ATOMIC_RELAXED,
                           __HIP_MEMORY_SCOPE_AGENT);
      }
    }
    zc0 = zn0;
    zc1 = zn1;
  }
}

__global__ __launch_bounds__(256) void k_logits(const float* __restrict__ H1,
                                                const float* __restrict__ Wout,
                                                const float* __restrict__ bout,
                                                float* __restrict__ LOG) {
  __shared__ float hl[1024];
  const int t = blockIdx.x;
  const int tid = threadIdx.x;
  float4* hl4 = (float4*)hl;
  if (tid < 128)
    hl4[tid] = ((const float4*)(H1 + (size_t)t * kH))[tid];
  else
    hl4[tid] = ((const float4*)(H1 + (size_t)(kS + t) * kH))[tid - 128];
  __syncthreads();
  const int v = tid >> 2, q = tid & 3;
  const float4* w4 = (const float4*)(Wout + (size_t)v * 1024);
  float4 a = {0, 0, 0, 0};
#pragma unroll 8
  for (int j = 0; j < 64; j++) {
    const int idx = j * 4 + q;
    const float4 w = w4[idx];
    const float4 x = hl4[idx];
    a.x += w.x * x.x; a.y += w.y * x.y; a.z += w.z * x.z; a.w += w.w * x.w;
  }
  float acc = (a.x + a.y) + (a.z + a.w);
  acc += __shfl_xor(acc, 1);
  acc += __shfl_xor(acc, 2);
  if (q == 0) LOG[(size_t)t * kV + v] = acc + bout[v];
}

__global__ __launch_bounds__(256) void k_viterbi(const float* __restrict__ LOG,
                                                 const float* __restrict__ trans,
                                                 int* __restrict__ out) {
  __shared__ float delta[64];
  __shared__ float redS[4 * 64];
  __shared__ int redA[4 * 64];
  __shared__ unsigned char bp[511 * 64];
  const int tid = threadIdx.x;
  const int c = tid & 63, q = tid >> 6;
  if (tid < 64) delta[tid] = LOG[tid];
  __syncthreads();
  for (int t = 1; t < kS; t++) {
    float best = -1e30f;
    int bi = 0;
#pragma unroll 4
    for (int pp = 0; pp < 16; pp++) {
      const int p = q * 16 + pp;
      const float sc = delta[p] + trans[p * 64 + c];
      if (sc > best) { best = sc; bi = p; }  // strict > == first-max (numpy)
    }
    redS[q * 64 + c] = best;
    redA[q * 64 + c] = bi;
    __syncthreads();
    if (tid < 64) {
      float b = redS[c];
      int a = redA[c];
      for (int qq = 1; qq < 4; qq++) {
        const float v2 = redS[qq * 64 + c];
        if (v2 > b) { b = v2; a = redA[qq * 64 + c]; }
      }
      bp[(t - 1) * 64 + c] = (unsigned char)a;
      delta[c] = b + LOG[t * 64 + c];
    }
    __syncthreads();
  }
  if (tid == 0) {
    float b = delta[0];
    int a = 0;
    for (int i = 1; i < 64; i++)
      if (delta[i] > b) { b = delta[i]; a = i; }
    int idx = a;
    out[kS - 1] = idx;
    for (int t = kS - 2; t >= 0; t--) {
      idx = bp[t * 64 + idx];
      out[t] = idx;
    }
  }
}

extern "C" void kernel_launch(void* const* d_in, const int* in_sizes, int n_in,
                              void* d_out, int out_size, void* d_ws,
                              size_t ws_size, hipStream_t stream) {
  (void)in_sizes; (void)n_in; (void)out_size; (void)ws_size;
  const int* source  = (const int*)d_in[0];
  const float* emb   = (const float*)d_in[2];
  const float* Wih0  = (const float*)d_in[3];
  const float* Whh0  = (const float*)d_in[4];
  const float* bih0  = (const float*)d_in[5];
  const float* bhh0  = (const float*)d_in[6];
  const float* Wih1  = (const float*)d_in[7];
  const float* Whh1  = (const float*)d_in[8];
  const float* bih1  = (const float*)d_in[9];
  const float* bhh1  = (const float*)d_in[10];
  const float* Wout  = (const float*)d_in[11];
  const float* bout  = (const float*)d_in[12];
  const float* trans = (const float*)d_in[13];

  float* ws = (float*)d_ws;
  float* X   = ws;
  float* H0  = ws + 262144;
  float* H1  = ws + 786432;
  float* LOG = ws + 1310720;

  // sentinel-init both handoff buffers (contiguous 4 MB): 0xFFFFFFFF is NaN,
  // unreachable for computed h. Must run every launch (re-poison).
  hipMemsetAsync(H0, 0xFF, (size_t)2 * 524288 * sizeof(float), stream);

  k_embed<<<kS, 128, 0, stream>>>(source, emb, X);
  k_rec<512><<<256, 512, 0, stream>>>(X, X, Wih0, Whh0, bih0, bhh0, H0);
  k_rec<1024><<<256, 512, 0, stream>>>(H0, H0 + 262144, Wih1, Whh1, bih1,
                                       bhh1, H1);
  k_logits<<<kS, 256, 0, stream>>>(H1, Wout, bout, LOG);
  k_viterbi<<<1, 256, 0, stream>>>(LOG, trans, (int*)d_out);
}

// Round 10
// 2352.272 us; speedup vs baseline: 1.0754x; 1.0754x over previous
//
#include <hip/hip_runtime.h>
#include <stdint.h>

constexpr int kS = 512;   // sequence length
constexpr int kB = 32;    // batch (only element 0 decoded)
constexpr int kH = 512;   // hidden
constexpr int kV = 64;    // tags

// ---------------------------------------------------------------------------
// ws layout (floats):
//   X    [512][512]      @ 0        (262144)
//   H0L  [2][512][512]   @ 262144   (524288)  XCD-local handoff copy (sc0/L2)
//   H0G  [2][512][512]   @ 786432   (524288)  agent/MALL copy
//   H1L  [2][512][512]   @ 1310720  (524288)
//   H1G  [2][512][512]   @ 1835008  (524288)
//   LOG  [512][64]       @ 2359296  (32768)
//   Xg0  [2][512][2048]  @ 2392064  (2097152)  input-gate sums L0 (+biases)
//   Xg1  [2][512][2048]  @ 4489216  (2097152)  input-gate sums L1 (+biases)
// Fast path needs 26,345,472 B; host checks ws_size, else falls back to the
// champion kernels (9.4 MB envelope).
//
// Evidence ledger (k_rec per-dispatch):
//  R0 champion 950us (5-try sc0 L2 + MALL, b%8 placement)   total 2022
//  R1/R2/R5/R7 handoff variants: 993-1214 (all worse)
//  R4 wave-autonomous: 4966 (5x) -> handoff micro-structure exhausted.
//  R8/R9: container died without counters (infra suspected: R1 1232s push,
//  R7 440s push, R8 bare Trio error). This is a RESUBMIT of R9's hypothesis:
// VALUBusy ~69% on active CUs vs ~35% hand-count => weight arrays (ww+zw >
// VGPR_Count=116) live in AGPR/scratch, bloating every MAC; the barrier puts
// the slowest wave's VALU tail on the critical path. Fix: hoist the input
// matvec into dependency-free GEMMs (k_xg, weight-stationary, t-chunked);
// k_rec_pre keeps ONLY the recurrent matvec (~90 VGPR, clean register fit).
// Handoff kept champion-verbatim. Third identical failure => kernel-side,
// revert to champion.
// ---------------------------------------------------------------------------

__device__ __forceinline__ float fast_sigmoid(float x) {
  return __builtin_amdgcn_rcpf(1.0f + __expf(-x));
}
__device__ __forceinline__ float fast_tanh(float x) {
  return 1.0f - 2.0f * __builtin_amdgcn_rcpf(1.0f + __expf(2.0f * x));
}
__device__ __forceinline__ float bcast(float v, int k) {
  return __uint_as_float(__builtin_amdgcn_readlane(__float_as_uint(v), k));
}
// L2-coherent (within one XCD) load/store: sc0 = bypass L1, serve from the
// XCD-shared L2. NOT cross-XCD coherent -- that's what the G-copy is for.
__device__ __forceinline__ unsigned ld_l2(const unsigned* p) {
  unsigned r;
  asm volatile("global_load_dword %0, %1, off sc0\n\ts_waitcnt vmcnt(0)"
               : "=v"(r) : "v"(p) : "memory");
  return r;
}
__device__ __forceinline__ void st_l2(unsigned* p, unsigned v) {
  asm volatile("global_store_dword %0, %1, off sc0" :: "v"(p), "v"(v)
               : "memory");
}
__device__ __forceinline__ unsigned ld_agent(const unsigned* p) {
  return __hip_atomic_load(p, __ATOMIC_RELAXED, __HIP_MEMORY_SCOPE_AGENT);
}

__global__ __launch_bounds__(128) void k_embed(const int* __restrict__ src,
                                               const float* __restrict__ emb,
                                               float* __restrict__ X) {
  const int t = blockIdx.x;
  const int s = src[t * kB];  // batch 0 token
  const float4* e = (const float4*)(emb + (size_t)s * 512);
  float4* x = (float4*)(X + (size_t)t * 512);
  x[threadIdx.x] = e[threadIdx.x];
}

// Input-gate GEMM: Xg[dir][t][row] = Wih[dir][row] . z_t + bih + bhh.
// No cross-block deps, no sentinels (stream order protects consumers).
// Grid 512: dir = b&1, rowslice rs = (b>>1)&31, t-chunk tc = b>>6 (8 chunks
// of 64 steps). Same (wave k-slice, lane gate-row) decomposition as the
// champion's input matvec; weights register-stationary across the chunk.
template <int KZ>
__global__ __launch_bounds__(512) void k_xg(
    const float* __restrict__ Z0,   // L0: X; L1: H0G fwd
    const float* __restrict__ Z1,   // L1: H0G bwd (unused for KZ==512)
    const float* __restrict__ Wih,  // [2][2048][KZ]
    const float* __restrict__ bih,  // [2][2048]
    const float* __restrict__ bhh,  // [2][2048]
    float* __restrict__ Xg) {       // [2][512][2048]
  constexpr int ZPW = KZ / 8;
  __shared__ float part[64 * 9];
  const int b = blockIdx.x;
  const int dir = b & 1, rs = (b >> 1) & 31, tc = b >> 6;
  const int tid = threadIdx.x;
  const int wv = tid >> 6, l = tid & 63;
  const int grow = (l >> 4) * 512 + rs * 16 + (l & 15);

  float zw[ZPW];
  {
    const float* zp = Wih + ((size_t)dir * 2048 + grow) * KZ + wv * ZPW;
#pragma unroll
    for (int i = 0; i < ZPW; i += 4) {
      const float4 v = *(const float4*)(zp + i);
      zw[i] = v.x; zw[i + 1] = v.y; zw[i + 2] = v.z; zw[i + 3] = v.w;
    }
  }
  float bias = 0.0f;
  if (wv == 0) bias = bih[dir * 2048 + grow] + bhh[dir * 2048 + grow];
  float* XgD = Xg + (size_t)dir * kS * 2048;

  const float* zbase = (KZ == 512) ? Z0 : ((wv < 4) ? Z0 : Z1);
  const int zoff = (KZ == 512) ? tid : ((wv & 3) * 128 + l);

  const int tbase = tc * 64;
  float zc0 = zbase[(size_t)tbase * 512 + zoff];
  float zc1 = (KZ == 1024) ? zbase[(size_t)tbase * 512 + zoff + 64] : 0.0f;

  for (int i = 0; i < 64; i++) {
    const int t = tbase + i;
    const int tn = (i < 63) ? (t + 1) : t;
    const float zn0 = zbase[(size_t)tn * 512 + zoff];
    const float zn1 = (KZ == 1024) ? zbase[(size_t)tn * 512 + zoff + 64] : 0.0f;

    float a0 = 0.f, a1 = 0.f, a2 = 0.f, a3 = 0.f;
#pragma unroll
    for (int k = 0; k < 64; k += 4) {
      a0 += zw[k + 0] * bcast(zc0, k + 0);
      a1 += zw[k + 1] * bcast(zc0, k + 1);
      a2 += zw[k + 2] * bcast(zc0, k + 2);
      a3 += zw[k + 3] * bcast(zc0, k + 3);
    }
    if (KZ == 1024) {
#pragma unroll
      for (int k = 0; k < 64; k += 4) {
        a0 += zw[64 + k + 0] * bcast(zc1, k + 0);
        a1 += zw[64 + k + 1] * bcast(zc1, k + 1);
        a2 += zw[64 + k + 2] * bcast(zc1, k + 2);
        a3 += zw[64 + k + 3] * bcast(zc1, k + 3);
      }
    }
    part[l * 9 + wv] = (a0 + a1) + (a2 + a3);
    __syncthreads();
    if (wv == 0) {
      float ssum = bias;
#pragma unroll
      for (int w = 0; w < 8; w++) ssum += part[l * 9 + w];
      XgD[(size_t)t * 2048 + grow] = ssum;
    }
    __syncthreads();  // part[] reuse fence (no timing slack in this kernel)
    zc0 = zn0;
    zc1 = zn1;
  }
}

// Recurrence with precomputed input gates. Champion structure/handoff
// VERBATIM minus the input matvec (zw gone -> ~90 VGPR, clean register fit).
// Grid 256, workers b%8 in {0,1} (dir=b%8, wg=b>>3); 1 block/CU co-resident.
__global__ __launch_bounds__(512, 1) void k_rec_pre(
    const float* __restrict__ Xg,   // [2][512][2048] gate sums (+biases)
    const float* __restrict__ Whh,  // [2][2048][512]
    float* __restrict__ HL,         // [2][512][512] local-L2 handoff copy
    float* __restrict__ HG) {       // [2][512][512] MALL copy (downstream)
  __shared__ float part[64 * 9];    // [row][wave], stride 9
  const int b = blockIdx.x;
  const int xslot = b & 7;
  if (xslot > 1) return;
  const int dir = xslot, wg = b >> 3;
  const int tid = threadIdx.x;
  const int wv = tid >> 6, l = tid & 63;
  const float* WhhB = Whh + (size_t)dir * 2048 * 512;
  const float* XgD = Xg + (size_t)dir * kS * 2048;
  float* HbL = HL + (size_t)dir * kS * kH;
  float* HbG = HG + (size_t)dir * kS * kH;
  const int grow = (l >> 4) * 512 + wg * 16 + (l & 15);

  float ww[64];
  {
    const float* wp = WhhB + (size_t)grow * 512 + wv * 64;
#pragma unroll
    for (int i = 0; i < 64; i += 4) {
      const float4 v = *(const float4*)(wp + i);
      ww[i] = v.x; ww[i + 1] = v.y; ww[i + 2] = v.z; ww[i + 3] = v.w;
    }
  }
  float cstate = 0.0f;  // live in wave 0, lanes < 16

  const int t0 = dir ? (kS - 1) : 0;
  float xgc = 0.0f;
  if (wv == 0) xgc = XgD[(size_t)t0 * 2048 + grow];

  for (int s = 0; s < kS; s++) {
    const int t = dir ? (kS - 1 - s) : s;
    int tn = dir ? (t - 1) : (t + 1);
    if (tn < 0) tn = 0;
    if (tn > kS - 1) tn = kS - 1;
    // next-step Xg prefetch (wave 0; independent, hides under poll)
    float xgn = 0.0f;
    if (wv == 0) xgn = XgD[(size_t)tn * 2048 + grow];

    // --- poll previous h: champion 5-try L2 prelude + MALL fallback ---
    float hreg = 0.0f;
    if (s > 0) {
      const int tp = dir ? (t + 1) : (t - 1);
      const unsigned* lp = (const unsigned*)(HbL + (size_t)tp * kH) + tid;
      const unsigned* gp = (const unsigned*)(HbG + (size_t)tp * kH) + tid;
      unsigned u = ld_l2(lp);
#pragma unroll 1
      for (int r = 0; r < 4; r++) {
        if (u != 0xFFFFFFFFu) break;
        u = ld_l2(lp);
      }
      while (u == 0xFFFFFFFFu) u = ld_agent(gp);
      hreg = __uint_as_float(u);
    }

    // --- recurrent matvec: readlane broadcast (only VALU work per step) ---
    float a0 = 0.f, a1 = 0.f, a2 = 0.f, a3 = 0.f;
#pragma unroll
    for (int k = 0; k < 64; k += 4) {
      a0 += ww[k + 0] * bcast(hreg, k + 0);
      a1 += ww[k + 1] * bcast(hreg, k + 1);
      a2 += ww[k + 2] * bcast(hreg, k + 2);
      a3 += ww[k + 3] * bcast(hreg, k + 3);
    }
    part[l * 9 + wv] = (a0 + a1) + (a2 + a3);
    __syncthreads();
    // waves 1..7 fall through to next step; wave 0 does the cell.
    if (wv == 0) {
      float ssum = xgc;
#pragma unroll
      for (int w = 0; w < 8; w++) ssum += part[l * 9 + w];
      const float sf = __shfl(ssum, (l + 16) & 63);
      const float sg = __shfl(ssum, (l + 32) & 63);
      const float so = __shfl(ssum, (l + 48) & 63);
      if (l < 16) {
        const float ig = fast_sigmoid(ssum);
        const float fg = fast_sigmoid(sf);
        const float og = fast_sigmoid(so);
        cstate = fg * cstate + ig * fast_tanh(sg);
        const float h = og * fast_tanh(cstate);
        const unsigned hv = __float_as_uint(h);
        unsigned* lq = (unsigned*)(HbL + (size_t)t * kH) + wg * 16 + l;
        unsigned* gq = (unsigned*)(HbG + (size_t)t * kH) + wg * 16 + l;
        st_l2(lq, hv);
        __hip_atomic_store(gq, hv, __ATOMIC_RELAXED,
                           __HIP_MEMORY_SCOPE_AGENT);
      }
      xgc = xgn;
    }
  }
}

// ---- champion k_rec (fallback path, verbatim from the 2022us kernel) ------
template <int KZ>
__global__ __launch_bounds__(512, 1) void k_rec(
    const float* __restrict__ Z0, const float* __restrict__ Z1,
    const float* __restrict__ Wih, const float* __restrict__ Whh,
    const float* __restrict__ bih, const float* __restrict__ bhh,
    float* __restrict__ HL, float* __restrict__ HG) {
  constexpr int ZPW = KZ / 8;
  __shared__ float part[64 * 9];
  const int b = blockIdx.x;
  const int xslot = b & 7;
  if (xslot > 1) return;
  const int dir = xslot, wg = b >> 3;
  const int tid = threadIdx.x;
  const int wv = tid >> 6, l = tid & 63;
  const float* WihB = Wih + (size_t)dir * 2048 * KZ;
  const float* WhhB = Whh + (size_t)dir * 2048 * 512;
  float* HbL = HL + (size_t)dir * kS * kH;
  float* HbG = HG + (size_t)dir * kS * kH;
  const int grow = (l >> 4) * 512 + wg * 16 + (l & 15);

  float ww[64];
  {
    const float* wp = WhhB + (size_t)grow * 512 + wv * 64;
#pragma unroll
    for (int i = 0; i < 64; i += 4) {
      const float4 v = *(const float4*)(wp + i);
      ww[i] = v.x; ww[i + 1] = v.y; ww[i + 2] = v.z; ww[i + 3] = v.w;
    }
  }
  float zw[ZPW];
  {
    const float* zp = WihB + (size_t)grow * KZ + wv * ZPW;
#pragma unroll
    for (int i = 0; i < ZPW; i += 4) {
      const float4 v = *(const float4*)(zp + i);
      zw[i] = v.x; zw[i + 1] = v.y; zw[i + 2] = v.z; zw[i + 3] = v.w;
    }
  }
  float bias = 0.0f;
  if (wv == 0) bias = bih[dir * 2048 + grow] + bhh[dir * 2048 + grow];
  float cstate = 0.0f;

  const float* zbase = (KZ == 512) ? Z0 : ((wv < 4) ? Z0 : Z1);
  const int zoff = (KZ == 512) ? tid : ((wv & 3) * 128 + l);

  const int t0 = dir ? (kS - 1) : 0;
  float zc0 = zbase[(size_t)t0 * 512 + zoff];
  float zc1 = (KZ == 1024) ? zbase[(size_t)t0 * 512 + zoff + 64] : 0.0f;

  for (int s = 0; s < kS; s++) {
    const int t = dir ? (kS - 1 - s) : s;
    int tn = dir ? (t - 1) : (t + 1);
    if (tn < 0) tn = 0;
    if (tn > kS - 1) tn = kS - 1;
    const float zn0 = zbase[(size_t)tn * 512 + zoff];
    const float zn1 = (KZ == 1024) ? zbase[(size_t)tn * 512 + zoff + 64] : 0.0f;

    float a0 = 0.f, a1 = 0.f, a2 = 0.f, a3 = 0.f;
#pragma unroll
    for (int k = 0; k < 64; k += 4) {
      a0 += zw[k + 0] * bcast(zc0, k + 0);
      a1 += zw[k + 1] * bcast(zc0, k + 1);
      a2 += zw[k + 2] * bcast(zc0, k + 2);
      a3 += zw[k + 3] * bcast(zc0, k + 3);
    }
    if (KZ == 1024) {
#pragma unroll
      for (int k = 0; k < 64; k += 4) {
        a0 += zw[64 + k + 0] * bcast(zc1, k + 0);
        a1 += zw[64 + k + 1] * bcast(zc1, k + 1);
        a2 += zw[64 + k + 2] * bcast(zc1, k + 2);
        a3 += zw[64 + k + 3] * bcast(zc1, k + 3);
      }
    }

    float hreg = 0.0f;
    if (s > 0) {
      const int tp = dir ? (t + 1) : (t - 1);
      const unsigned* lp = (const unsigned*)(HbL + (size_t)tp * kH) + tid;
      const unsigned* gp = (const unsigned*)(HbG + (size_t)tp * kH) + tid;
      unsigned u = ld_l2(lp);
#pragma unroll 1
      for (int r = 0; r < 4; r++) {
        if (u != 0xFFFFFFFFu) break;
        u = ld_l2(lp);
      }
      while (u == 0xFFFFFFFFu) u = ld_agent(gp);
      hreg = __uint_as_float(u);
    }

#pragma unroll
    for (int k = 0; k < 64; k += 4) {
      a0 += ww[k + 0] * bcast(hreg, k + 0);
      a1 += ww[k + 1] * bcast(hreg, k + 1);
      a2 += ww[k + 2] * bcast(hreg, k + 2);
      a3 += ww[k + 3] * bcast(hreg, k + 3);
    }
    part[l * 9 + wv] = (a0 + a1) + (a2 + a3);
    __syncthreads();
    if (wv == 0) {
      float ssum = bias;
#pragma unroll
      for (int w = 0; w < 8; w++) ssum += part[l * 9 + w];
      const float sf = __shfl(ssum, (l + 16) & 63);
      const float sg = __shfl(ssum, (l + 32) & 63);
      const float so = __shfl(ssum, (l + 48) & 63);
      if (l < 16) {
        const float ig = fast_sigmoid(ssum);
        const float fg = fast_sigmoid(sf);
        const float og = fast_sigmoid(so);
        cstate = fg * cstate + ig * fast_tanh(sg);
        const float h = og * fast_tanh(cstate);
        const unsigned hv = __float_as_uint(h);
        unsigned* lq = (unsigned*)(HbL + (size_t)t * kH) + wg * 16 + l;
        unsigned* gq = (unsigned*)(HbG + (size_t)t * kH) + wg * 16 + l;
        st_l2(lq, hv);
        __hip_atomic_store(gq, hv, __ATOMIC_RELAXED,
                           __HIP_MEMORY_SCOPE_AGENT);
      }
    }
    zc0 = zn0;
    zc1 = zn1;
  }
}

__global__ __launch_bounds__(256) void k_logits(const float* __restrict__ H1,
                                                const float* __restrict__ Wout,
                                                const float* __restrict__ bout,
                                                float* __restrict__ LOG) {
  __shared__ float hl[1024];
  const int t = blockIdx.x;
  const int tid = threadIdx.x;
  float4* hl4 = (float4*)hl;
  if (tid < 128)
    hl4[tid] = ((const float4*)(H1 + (size_t)t * kH))[tid];
  else
    hl4[tid] = ((const float4*)(H1 + (size_t)(kS + t) * kH))[tid - 128];
  __syncthreads();
  const int v = tid >> 2, q = tid & 3;
  const float4* w4 = (const float4*)(Wout + (size_t)v * 1024);
  float4 a = {0, 0, 0, 0};
#pragma unroll 8
  for (int j = 0; j < 64; j++) {
    const int idx = j * 4 + q;
    const float4 w = w4[idx];
    const float4 x = hl4[idx];
    a.x += w.x * x.x; a.y += w.y * x.y; a.z += w.z * x.z; a.w += w.w * x.w;
  }
  float acc = (a.x + a.y) + (a.z + a.w);
  acc += __shfl_xor(acc, 1);
  acc += __shfl_xor(acc, 2);
  if (q == 0) LOG[(size_t)t * kV + v] = acc + bout[v];
}

__global__ __launch_bounds__(256) void k_viterbi(const float* __restrict__ LOG,
                                                 const float* __restrict__ trans,
                                                 int* __restrict__ out) {
  __shared__ float delta[64];
  __shared__ float redS[4 * 64];
  __shared__ int redA[4 * 64];
  __shared__ unsigned char bp[511 * 64];
  const int tid = threadIdx.x;
  const int c = tid & 63, q = tid >> 6;
  if (tid < 64) delta[tid] = LOG[tid];
  __syncthreads();
  for (int t = 1; t < kS; t++) {
    float best = -1e30f;
    int bi = 0;
#pragma unroll 4
    for (int pp = 0; pp < 16; pp++) {
      const int p = q * 16 + pp;
      const float sc = delta[p] + trans[p * 64 + c];
      if (sc > best) { best = sc; bi = p; }  // strict > == first-max (numpy)
    }
    redS[q * 64 + c] = best;
    redA[q * 64 + c] = bi;
    __syncthreads();
    if (tid < 64) {
      float b = redS[c];
      int a = redA[c];
      for (int qq = 1; qq < 4; qq++) {
        const float v2 = redS[qq * 64 + c];
        if (v2 > b) { b = v2; a = redA[qq * 64 + c]; }
      }
      bp[(t - 1) * 64 + c] = (unsigned char)a;
      delta[c] = b + LOG[t * 64 + c];
    }
    __syncthreads();
  }
  if (tid == 0) {
    float b = delta[0];
    int a = 0;
    for (int i = 1; i < 64; i++)
      if (delta[i] > b) { b = delta[i]; a = i; }
    int idx = a;
    out[kS - 1] = idx;
    for (int t = kS - 2; t >= 0; t--) {
      idx = bp[t * 64 + idx];
      out[t] = idx;
    }
  }
}

extern "C" void kernel_launch(void* const* d_in, const int* in_sizes, int n_in,
                              void* d_out, int out_size, void* d_ws,
                              size_t ws_size, hipStream_t stream) {
  (void)in_sizes; (void)n_in; (void)out_size;
  const int* source  = (const int*)d_in[0];
  const float* emb   = (const float*)d_in[2];
  const float* Wih0  = (const float*)d_in[3];
  const float* Whh0  = (const float*)d_in[4];
  const float* bih0  = (const float*)d_in[5];
  const float* bhh0  = (const float*)d_in[6];
  const float* Wih1  = (const float*)d_in[7];
  const float* Whh1  = (const float*)d_in[8];
  const float* bih1  = (const float*)d_in[9];
  const float* bhh1  = (const float*)d_in[10];
  const float* Wout  = (const float*)d_in[11];
  const float* bout  = (const float*)d_in[12];
  const float* trans = (const float*)d_in[13];

  float* ws = (float*)d_ws;
  float* X   = ws;
  float* H0L = ws + 262144;
  float* H0G = ws + 786432;
  float* H1L = ws + 1310720;
  float* H1G = ws + 1835008;
  float* LOG = ws + 2359296;
  float* Xg0 = ws + 2392064;
  float* Xg1 = ws + 4489216;

  // sentinel-init the four handoff buffers (contiguous 8 MB): 0xFFFFFFFF is
  // NaN, unreachable for computed h. Must run every launch (re-poison).
  hipMemsetAsync(H0L, 0xFF, (size_t)4 * 524288 * sizeof(float), stream);

  k_embed<<<kS, 128, 0, stream>>>(source, emb, X);

  const size_t need = (size_t)(4489216 + 2097152) * sizeof(float);  // 26.3 MB
  if (ws_size >= need) {
    // fast path: hoisted input-gate GEMMs + slim recurrence
    k_xg<512><<<512, 512, 0, stream>>>(X, X, Wih0, bih0, bhh0, Xg0);
    k_rec_pre<<<256, 512, 0, stream>>>(Xg0, Whh0, H0L, H0G);
    k_xg<1024><<<512, 512, 0, stream>>>(H0G, H0G + 262144, Wih1, bih1, bhh1,
                                        Xg1);
    k_rec_pre<<<256, 512, 0, stream>>>(Xg1, Whh1, H1L, H1G);
  } else {
    // fallback: champion verbatim (9.4 MB envelope)
    k_rec<512><<<256, 512, 0, stream>>>(X, X, Wih0, Whh0, bih0, bhh0, H0L,
                                        H0G);
    k_rec<1024><<<256, 512, 0, stream>>>(H0G, H0G + 262144, Wih1, Whh1, bih1,
                                         bhh1, H1L, H1G);
  }

  k_logits<<<kS, 256, 0, stream>>>(H1G, Wout, bout, LOG);
  k_viterbi<<<1, 256, 0, stream>>>(LOG, trans, (int*)d_out);
}